// Round 17
// baseline (133.917 us; speedup 1.0000x reference)
//
#include <hip/hip_runtime.h>
#include <hip/hip_fp16.h>

typedef _Float16 f16;
typedef _Float16 half8 __attribute__((ext_vector_type(8)));
typedef _Float16 half4v __attribute__((ext_vector_type(4)));
typedef __fp16 fp16x2 __attribute__((ext_vector_type(2)));   // cvt_pkrtz result type
typedef float f32x4 __attribute__((ext_vector_type(4)));

// Q pre-scale: d^-0.5 (=0.125) * log2(e), so attn computes P=2^(s'-12*log2e)
#define QSCALE 0.18033688011112042f
#define SHIFT2 17.312340490667560f   // 12 * log2(e)

__device__ __forceinline__ void gload_lds16(const void* g, void* lds) {
  __builtin_amdgcn_global_load_lds(
      (__attribute__((address_space(1))) void*)g,
      (__attribute__((address_space(3))) void*)lds, 16, 0, 0);
}

// ---------------- fp32 -> fp16 convert (all three inputs, one launch) ------
__global__ __launch_bounds__(256) void cvt_all_kernel(
    const float* __restrict__ x, const float* __restrict__ wqkv,
    const float* __restrict__ wproj, f16* __restrict__ xh,
    f16* __restrict__ wqkvh, f16* __restrict__ wprojh) {
  int i = blockIdx.x * 256 + threadIdx.x;      // 0 .. 2097151 (exact grid)
  const float* src; f16* dst; int off;
  if (i < 1048576)      { src = x;     dst = xh;     off = i; }
  else if (i < 1835008) { src = wqkv;  dst = wqkvh;  off = i - 1048576; }
  else                  { src = wproj; dst = wprojh; off = i - 1835008; }
  float4 v = ((const float4*)src)[off];
  half4v o;
  o.x = (f16)v.x; o.y = (f16)v.y; o.z = (f16)v.z; o.w = (f16)v.w;
  ((half4v*)dst)[off] = o;
}

// ---------------- QKV HGEMM: 256x256 8-phase (T3+T4+T5) --------------------
// C = A*B^T, A [4096,1024] f16, B [3072,1024] f16. BM=BN=256, BK=64.
// 512 threads = 8 waves (2M x 4N); per-wave out 128x64 (acc[8][4]).
// Per K-tile: 4 phases = C-quadrant x 16 MFMA, setprio around each cluster.
// Staging: all 4 half-tiles of tile t+1 front-loaded at tile t start; ONE
// vmcnt(0) drain per 64-K tile, covered by ~4 phases of compute.
// WAR: buf^1 last read at tile t-1; reads complete before t-1's MFMAs issue,
// which precede the boundary barrier => stage-after-barrier safe.
// LDS [256][64] f16, sub-swizzle sub^=(row&7) (16B subs): staging = 8 lanes
// per contiguous 128B row; frag reads uniform 8 lanes/sub => conflict-free.
// Epilogue: QKV + RoPE -> Q,K ([bh][2048][64]) and V^T ([bh][64][2048]).
__global__ __launch_bounds__(512, 1) void hgemm8p_kernel(
    const f16* __restrict__ A16, const f16* __restrict__ B,
    const float* __restrict__ cosT, const float* __restrict__ sinT,
    f16* __restrict__ Qout, f16* __restrict__ Kout, f16* __restrict__ Vtout) {
  constexpr int K = 1024;
  __shared__ f16 As[2][256 * 64];
  __shared__ f16 Bs[2][256 * 64];
  const int tid = threadIdx.x;                 // 0..511
  const int lane = tid & 63, w = tid >> 6;     // 8 waves
  const int fr = lane & 15, fkg = lane >> 4;
  const int wr = w >> 2, wc = w & 3;           // 2M x 4N wave grid

  // XCD-chunked swizzle over 192 blocks: each XCD gets 2 M-rows x 12 N-cols
  const int lin = blockIdx.x;
  const int wgid = (lin & 7) * 24 + (lin >> 3);
  const int bm = wgid / 12, bn = wgid % 12;
  const long long rowBase = (long long)bm * 256;
  const long long colBase = (long long)bn * 256;

  f32x4 acc[8][4] = {};
  const f16* Ab = A16 + rowBase * K;
  const f16* Bb = B + colBase * K;

  // staging map: half-tile = 128 rows x 8 subs(16B); thread t covers slots
  // t and t+512; LDS slot (row,sd) <- global (row, sd^(row&7)).
  int srow[2], scol[2], sdst[2];
#pragma unroll
  for (int p = 0; p < 2; ++p) {
    int slot = p * 512 + tid;
    int row = slot >> 3, sd = slot & 7;
    srow[p] = row;
    scol[p] = (sd ^ (row & 7)) * 8;            // halfs
    sdst[p] = row * 64 + sd * 8;
  }

  auto stageTile = [&](int buf, int k0) {      // 4 half-tiles (A0,A1,B0,B1)
#pragma unroll
    for (int p = 0; p < 2; ++p) {
      gload_lds16(Ab + (long long)srow[p] * K + k0 + scol[p], &As[buf][sdst[p]]);
      gload_lds16(Ab + (long long)(128 + srow[p]) * K + k0 + scol[p],
                  &As[buf][128 * 64 + sdst[p]]);
      gload_lds16(Bb + (long long)srow[p] * K + k0 + scol[p], &Bs[buf][sdst[p]]);
      gload_lds16(Bb + (long long)(128 + srow[p]) * K + k0 + scol[p],
                  &Bs[buf][128 * 64 + sdst[p]]);
    }
  };

  // fragment addressing: row = base + tile*16 + fr; sub = (kk*4+fkg)^(fr&7)
  const int arow = wr * 128 + fr;
  const int brow = wc * 64 + fr;
  const int sub0 = ((0 + fkg) ^ (fr & 7)) * 8;   // kk=0
  const int sub1 = ((4 + fkg) ^ (fr & 7)) * 8;   // kk=1

  stageTile(0, 0);
  for (int t = 0; t < 16; ++t) {
    const int buf = t & 1;
    asm volatile("s_waitcnt vmcnt(0)" ::: "memory");   // tile t landed
    __builtin_amdgcn_s_barrier();                      // all waves agree
    __builtin_amdgcn_sched_barrier(0);
    if (t + 1 < 16) stageTile(buf ^ 1, (t + 1) << 6);  // front-load next tile

    half8 a[4][2], b0[2][2], b1[2][2];
    // ---- P1: quadrant (mh0, nh0) ---- 12 ds_read + 16 MFMA
#pragma unroll
    for (int i = 0; i < 4; ++i) {
      a[i][0] = *(const half8*)(&As[buf][(arow + i * 16) * 64 + sub0]);
      a[i][1] = *(const half8*)(&As[buf][(arow + i * 16) * 64 + sub1]);
    }
#pragma unroll
    for (int j = 0; j < 2; ++j) {
      b0[j][0] = *(const half8*)(&Bs[buf][(brow + j * 16) * 64 + sub0]);
      b0[j][1] = *(const half8*)(&Bs[buf][(brow + j * 16) * 64 + sub1]);
    }
    __builtin_amdgcn_s_setprio(1);
#pragma unroll
    for (int i = 0; i < 4; ++i)
#pragma unroll
      for (int j = 0; j < 2; ++j)
#pragma unroll
        for (int kk = 0; kk < 2; ++kk)
          acc[i][j] = __builtin_amdgcn_mfma_f32_16x16x32_f16(a[i][kk], b0[j][kk], acc[i][j], 0, 0, 0);
    __builtin_amdgcn_s_setprio(0);
    __builtin_amdgcn_s_barrier();
    // ---- P2: quadrant (mh0, nh1) ---- 4 ds_read + 16 MFMA
#pragma unroll
    for (int j = 0; j < 2; ++j) {
      b1[j][0] = *(const half8*)(&Bs[buf][(brow + (j + 2) * 16) * 64 + sub0]);
      b1[j][1] = *(const half8*)(&Bs[buf][(brow + (j + 2) * 16) * 64 + sub1]);
    }
    __builtin_amdgcn_s_setprio(1);
#pragma unroll
    for (int i = 0; i < 4; ++i)
#pragma unroll
      for (int j = 0; j < 2; ++j)
#pragma unroll
        for (int kk = 0; kk < 2; ++kk)
          acc[i][j + 2] = __builtin_amdgcn_mfma_f32_16x16x32_f16(a[i][kk], b1[j][kk], acc[i][j + 2], 0, 0, 0);
    __builtin_amdgcn_s_setprio(0);
    __builtin_amdgcn_s_barrier();
    // ---- P3: quadrant (mh1, nh0) ---- 8 ds_read + 16 MFMA
#pragma unroll
    for (int i = 0; i < 4; ++i) {
      a[i][0] = *(const half8*)(&As[buf][(arow + (i + 4) * 16) * 64 + sub0]);
      a[i][1] = *(const half8*)(&As[buf][(arow + (i + 4) * 16) * 64 + sub1]);
    }
    __builtin_amdgcn_s_setprio(1);
#pragma unroll
    for (int i = 0; i < 4; ++i)
#pragma unroll
      for (int j = 0; j < 2; ++j)
#pragma unroll
        for (int kk = 0; kk < 2; ++kk)
          acc[i + 4][j] = __builtin_amdgcn_mfma_f32_16x16x32_f16(a[i][kk], b0[j][kk], acc[i + 4][j], 0, 0, 0);
    __builtin_amdgcn_s_setprio(0);
    __builtin_amdgcn_s_barrier();
    // ---- P4: quadrant (mh1, nh1) ---- 0 ds_read + 16 MFMA
    __builtin_amdgcn_s_setprio(1);
#pragma unroll
    for (int i = 0; i < 4; ++i)
#pragma unroll
      for (int j = 0; j < 2; ++j)
#pragma unroll
        for (int kk = 0; kk < 2; ++kk)
          acc[i + 4][j + 2] = __builtin_amdgcn_mfma_f32_16x16x32_f16(a[i][kk], b1[j][kk], acc[i + 4][j + 2], 0, 0, 0);
    __builtin_amdgcn_s_setprio(0);
    // boundary vmcnt+barrier at next loop top
  }

  // epilogue: qkv col = t*1024 + head*64 + d; t/head wave-uniform (64-col span)
  const int cb0 = (int)colBase + wc * 64;
  const int tcol = cb0 >> 10;
  const int head = (cb0 & 1023) >> 6;
#pragma unroll
  for (int i = 0; i < 8; ++i) {
#pragma unroll
    for (int r = 0; r < 4; ++r) {
      int rg = (int)rowBase + wr * 128 + i * 16 + fkg * 4 + r;  // 0..4095
      int bidx = rg >> 11, nn = rg & 2047;
      int bh = bidx * 16 + head;
      if (tcol == 2) {
#pragma unroll
        for (int j = 0; j < 4; ++j) {
          int d = j * 16 + fr;
          Vtout[((long long)bh * 64 + d) * 2048 + nn] = (f16)acc[i][j][r];
        }
      } else {
#pragma unroll
        for (int j = 0; j < 4; ++j) {
          int d = j * 16 + fr;
          float v = acc[i][j][r];
          float pal = acc[i][j ^ 2][r];                // partner col d^32
          float cs = cosT[nn * 64 + d];
          float sn = sinT[nn * 64 + d];
          v = v * cs + (d < 32 ? -pal : pal) * sn;     // rotate_half
          if (tcol == 0) v *= QSCALE;                  // d^-0.5 * log2e
          f16 hv = (f16)v;
          if (tcol == 0) Qout[((long long)bh * 2048 + nn) * 64 + d] = hv;
          else           Kout[((long long)bh * 2048 + nn) * 64 + d] = hv;
        }
      }
    }
  }
}

// ---------------- out-proj HGEMM (FROZEN, round-9 proven) ------------------
// BM=128, BN=64, BK=32; 2-buffer counted-vmcnt loop; bias epilogue.
__global__ __launch_bounds__(256) void hgemm_out_kernel(
    const f16* __restrict__ A16, const f16* __restrict__ B, int K,
    const float* __restrict__ bias, float* __restrict__ Cout) {
  __shared__ f16 As[2][128 * 32];
  __shared__ f16 Bs[2][64 * 32];
  const int tid = threadIdx.x;
  const int lane = tid & 63, w = tid >> 6;
  const int fr = lane & 15, fkg = lane >> 4;
  const int wm = (w >> 1) * 64;
  const int wn = (w & 1) * 16;
  const long long rowBase = (long long)blockIdx.x * 128;
  const long long colBase = (long long)blockIdx.y * 64;

  f32x4 acc[4][2] = {};
  const f16* Ab = A16 + rowBase * K;
  const f16* Bb = B + colBase * K;

  const int srow = lane >> 2;
  const int kcol = ((lane & 3) ^ ((lane >> 3) & 3)) * 8;
  const int sw = (fkg ^ ((fr >> 1) & 3)) * 8;

  auto stage = [&](int buf, int k0) {
#pragma unroll
    for (int r = 0; r < 2; ++r) {
      int c = r * 4 + w;
      gload_lds16(Ab + (long long)(c * 16 + srow) * K + k0 + kcol, &As[buf][c * 512]);
    }
    int c = w;
    gload_lds16(Bb + (long long)(c * 16 + srow) * K + k0 + kcol, &Bs[buf][c * 512]);
  };

  const int NT = K >> 5;
  stage(0, 0);
  stage(1, 32);
  for (int t = 0; t < NT; ++t) {
    const int buf = t & 1;
    const int k0 = t << 5;
    if (t + 1 < NT) asm volatile("s_waitcnt vmcnt(3)" ::: "memory");
    else            asm volatile("s_waitcnt vmcnt(0)" ::: "memory");
    __builtin_amdgcn_s_barrier();
    __builtin_amdgcn_sched_barrier(0);
    half8 a[4], b[2];
#pragma unroll
    for (int i = 0; i < 4; ++i)
      a[i] = *(const half8*)(&As[buf][((wm >> 4) + i) * 512 + fr * 32 + sw]);
#pragma unroll
    for (int j = 0; j < 2; ++j)
      b[j] = *(const half8*)(&Bs[buf][((wn >> 4) + j * 2) * 512 + fr * 32 + sw]);
    asm volatile("s_waitcnt lgkmcnt(0)" ::: "memory");
    __builtin_amdgcn_sched_barrier(0);
    __builtin_amdgcn_s_barrier();
    if (t + 2 < NT) stage(buf, k0 + 64);
#pragma unroll
    for (int i = 0; i < 4; ++i)
#pragma unroll
      for (int j = 0; j < 2; ++j)
        acc[i][j] = __builtin_amdgcn_mfma_f32_16x16x32_f16(a[i], b[j], acc[i][j], 0, 0, 0);
  }

#pragma unroll
  for (int i = 0; i < 4; ++i)
#pragma unroll
    for (int r = 0; r < 4; ++r) {
      long long rg = rowBase + wm + i * 16 + fkg * 4 + r;
#pragma unroll
      for (int j = 0; j < 2; ++j) {
        int cg = (int)colBase + wn + j * 32 + fr;
        Cout[rg * 1024 + cg] = acc[i][j][r] + bias[cg];
      }
    }
}

// ---------------- flash attention (round-16, frozen) -----------------------
__global__ __launch_bounds__(256) void attn_kernel(
    const f16* __restrict__ Q, const f16* __restrict__ Kb,
    const f16* __restrict__ Vt, f16* __restrict__ Om) {
  __shared__ f16 Ks[2][64 * 64];
  __shared__ f16 Vs[2][64 * 64];
  const int tid = threadIdx.x;
  const int lane = tid & 63, w = tid >> 6;
  const int fr = lane & 15, fkg = lane >> 4, fk = fkg * 8;

  const int lin = blockIdx.x;
  const int slot = lin >> 3;
  const int bh = (lin & 7) * 4 + (slot >> 4);
  const int q0 = (slot & 15) * 128 + w * 32;

  const f16* Kbh = Kb + (long long)bh * 2048 * 64;
  const f16* Vbh = Vt + (long long)bh * 64 * 2048;

  half8 aq[2][2];
#pragma unroll
  for (int m = 0; m < 2; ++m)
#pragma unroll
    for (int ks = 0; ks < 2; ++ks)
      aq[m][ks] = *(const half8*)(Q + ((long long)bh * 2048 + q0 + m * 16 + fr) * 64 +
                                  ks * 32 + fk);

  half8 ones_frag;
#pragma unroll
  for (int j = 0; j < 8; ++j) ones_frag[j] = (fr == 0) ? (f16)1.0f : (f16)0.0f;

  f32x4 acc[2][4] = {};
  f32x4 accL[2] = {};

  const int srow = lane >> 3;
  const int ssub = ((lane & 7) ^ srow) * 8;
  long long koff[2], voff[2];
  int ldst[2];
#pragma unroll
  for (int c = 0; c < 2; ++c) {
    int R = w * 16 + c * 8 + srow;
    int pr = (R & 0x23) | ((R & 0x0C) << 1) | ((R & 0x10) >> 2);
    koff[c] = (long long)pr * 64 + ssub;
    voff[c] = (long long)R * 2048 + ssub;
    ldst[c] = (w * 16 + c * 8) * 64;
  }
  const f16* kpt = Kbh;
  const f16* vpt = Vbh;

  auto stage = [&](int buf) {
#pragma unroll
    for (int c = 0; c < 2; ++c) {
      gload_lds16(kpt + koff[c], &Ks[buf][ldst[c]]);
      gload_lds16(vpt + voff[c], &Vs[buf][ldst[c]]);
    }
    kpt += 4096;
    vpt += 64;
  };

  stage(0);
  stage(1);

  const float negshift = -SHIFT2;
  auto body = [&](int t, int buf) {
    if (t < 31) asm volatile("s_waitcnt vmcnt(4)" ::: "memory");
    else        asm volatile("s_waitcnt vmcnt(0)" ::: "memory");
    __builtin_amdgcn_s_barrier();
    __builtin_amdgcn_sched_barrier(0);

    f32x4 z[2][4];
#pragma unroll
    for (int n = 0; n < 4; ++n) {
      half8 bk0 = *(const half8*)(&Ks[buf][(n * 16 + fr) * 64 + ((fkg ^ (fr & 7)) * 8)]);
      half8 bk1 = *(const half8*)(&Ks[buf][(n * 16 + fr) * 64 + (((4 | fkg) ^ (fr & 7)) * 8)]);
#pragma unroll
      for (int m = 0; m < 2; ++m) {
        f32x4 tz = {negshift, negshift, negshift, negshift};
        tz = __builtin_amdgcn_mfma_f32_16x16x32_f16(bk0, aq[m][0], tz, 0, 0, 0);
        tz = __builtin_amdgcn_mfma_f32_16x16x32_f16(bk1, aq[m][1], tz, 0, 0, 0);
        z[m][n] = tz;
      }
    }

    half8 av[2][4];
#pragma unroll
    for (int ks = 0; ks < 2; ++ks)
#pragma unroll
      for (int dd = 0; dd < 4; ++dd)
        av[ks][dd] = *(const half8*)(&Vs[buf][(dd * 16 + fr) * 64 +
                                              ((((ks << 2) | fkg) ^ (fr & 7)) * 8)]);

    half8 ap[2][2];
#pragma unroll
    for (int m = 0; m < 2; ++m)
#pragma unroll
      for (int ks = 0; ks < 2; ++ks) {
        union { half8 v; fp16x2 p[4]; } u;
        u.p[0] = __builtin_amdgcn_cvt_pkrtz(
            __builtin_amdgcn_exp2f(z[m][2 * ks][0]),
            __builtin_amdgcn_exp2f(z[m][2 * ks][1]));
        u.p[1] = __builtin_amdgcn_cvt_pkrtz(
            __builtin_amdgcn_exp2f(z[m][2 * ks][2]),
            __builtin_amdgcn_exp2f(z[m][2 * ks][3]));
        u.p[2] = __builtin_amdgcn_cvt_pkrtz(
            __builtin_amdgcn_exp2f(z[m][2 * ks + 1][0]),
            __builtin_amdgcn_exp2f(z[m][2 * ks + 1][1]));
        u.p[3] = __builtin_amdgcn_cvt_pkrtz(
            __builtin_amdgcn_exp2f(z[m][2 * ks + 1][2]),
            __builtin_amdgcn_exp2f(z[m][2 * ks + 1][3]));
        ap[m][ks] = u.v;
      }

#pragma unroll
    for (int ks = 0; ks < 2; ++ks) {
#pragma unroll
      for (int m = 0; m < 2; ++m)
        accL[m] = __builtin_amdgcn_mfma_f32_16x16x32_f16(ones_frag, ap[m][ks], accL[m], 0, 0, 0);
#pragma unroll
      for (int dd = 0; dd < 4; ++dd)
#pragma unroll
        for (int m = 0; m < 2; ++m)
          acc[m][dd] = __builtin_amdgcn_mfma_f32_16x16x32_f16(av[ks][dd], ap[m][ks], acc[m][dd], 0, 0, 0);
    }

    asm volatile("s_waitcnt lgkmcnt(0)" ::: "memory");
    __builtin_amdgcn_sched_barrier(0);
    __builtin_amdgcn_s_barrier();
    if (t < 30) stage(buf);
  };

  for (int t = 0; t < 32; t += 2) {
    body(t, 0);
    body(t + 1, 1);
  }

  const int b = bh >> 4, h = bh & 15;
#pragma unroll
  for (int m = 0; m < 2; ++m) {
    float l = __shfl(accL[m][0], fr);
    float inv = 1.f / l;
#pragma unroll
    for (int dd = 0; dd < 4; ++dd) {
      half4v o;
#pragma unroll
      for (int r = 0; r < 4; ++r) o[r] = (f16)(acc[m][dd][r] * inv);
      *(half4v*)(&Om[((long long)b * 2048 + q0 + m * 16 + fr) * 1024 +
                     h * 64 + dd * 16 + fkg * 4]) = o;
    }
  }
}

extern "C" void kernel_launch(void* const* d_in, const int* in_sizes, int n_in,
                              void* d_out, int out_size, void* d_ws, size_t ws_size,
                              hipStream_t stream) {
  (void)in_sizes; (void)n_in; (void)out_size; (void)ws_size;
  const float* x     = (const float*)d_in[0];   // [2,2048,1024]
  const float* Wqkv  = (const float*)d_in[1];   // [3072,1024]
  const float* Wproj = (const float*)d_in[2];   // [1024,1024]
  const float* bproj = (const float*)d_in[3];   // [1024]
  const float* sinT  = (const float*)d_in[4];   // [2048,64]
  const float* cosT  = (const float*)d_in[5];   // [2048,64]
  float* out = (float*)d_out;                   // [2,2048,1024] fp32

  // 40 MB layout (evidenced since round 4). Om aliases xh (dead after QKV
  // GEMM; same-stream ordering).
  f16* ws     = (f16*)d_ws;
  f16* xh     = ws;                    // [0, 4194304)
  f16* Om     = ws;                    // [0, 4194304)  (after hgemm8p)
  f16* Wqkvh  = ws + 4194304;          // [4194304, 7340032)
  f16* Wprojh = ws + 7340032;          // [7340032, 8388608)
  f16* Qb     = ws + 8388608;          // [8388608, 12582912)   [32][2048][64]
  f16* Kb     = ws + 12582912;         // [12582912, 16777216)  [32][2048][64]
  f16* Vtb    = ws + 16777216;         // [16777216, 20971520)  [32][64][2048]

  cvt_all_kernel<<<8192, 256, 0, stream>>>(x, Wqkv, Wproj, xh, Wqkvh, Wprojh);

  hgemm8p_kernel<<<192, 512, 0, stream>>>(
      xh, Wqkvh, cosT, sinT, Qb, Kb, Vtb);

  attn_kernel<<<512, 256, 0, stream>>>(Qb, Kb, Vtb, Om);

  hgemm_out_kernel<<<dim3(32, 16), 256, 0, stream>>>(
      Om, Wprojh, 1024, bproj, out);
}

// Round 19
// 120.450 us; speedup vs baseline: 1.1118x; 1.1118x over previous
//
#include <hip/hip_runtime.h>
#include <hip/hip_fp16.h>

typedef _Float16 f16;
typedef _Float16 half8 __attribute__((ext_vector_type(8)));
typedef _Float16 half4v __attribute__((ext_vector_type(4)));
typedef __fp16 fp16x2 __attribute__((ext_vector_type(2)));   // cvt_pkrtz result type
typedef float f32x4 __attribute__((ext_vector_type(4)));

// Q pre-scale: d^-0.5 (=0.125) * log2(e), so attn computes P=2^(s'-12*log2e)
#define QSCALE 0.18033688011112042f
#define SHIFT2 17.312340490667560f   // 12 * log2(e)

__device__ __forceinline__ void gload_lds16(const void* g, void* lds) {
  __builtin_amdgcn_global_load_lds(
      (__attribute__((address_space(1))) void*)g,
      (__attribute__((address_space(3))) void*)lds, 16, 0, 0);
}

// ---------------- fp32 -> fp16 convert (all three inputs, one launch) ------
__global__ __launch_bounds__(256) void cvt_all_kernel(
    const float* __restrict__ x, const float* __restrict__ wqkv,
    const float* __restrict__ wproj, f16* __restrict__ xh,
    f16* __restrict__ wqkvh, f16* __restrict__ wprojh) {
  int i = blockIdx.x * 256 + threadIdx.x;      // 0 .. 2097151 (exact grid)
  const float* src; f16* dst; int off;
  if (i < 1048576)      { src = x;     dst = xh;     off = i; }
  else if (i < 1835008) { src = wqkv;  dst = wqkvh;  off = i - 1048576; }
  else                  { src = wproj; dst = wprojh; off = i - 1835008; }
  float4 v = ((const float4*)src)[off];
  half4v o;
  o.x = (f16)v.x; o.y = (f16)v.y; o.z = (f16)v.z; o.w = (f16)v.w;
  ((half4v*)dst)[off] = o;
}

// ---------------- HGEMM: C = A * B^T  (VAR0 ONLY — race-safe ledger) -------
// BM=128, BK=32; EPI0: BN=128 (RoPE partner j^2); EPI1: BN=64.
// 2-buffer, 2-barrier loop: ds_reads -> lgkmcnt(0) asm (memory clobber, pins
// reads ABOVE the barrier) -> sched_barrier -> s_barrier -> stage. The VAR1
// single-barrier variant was removed: its WAR safety relied on the compiler
// not sinking ds_reads past a raw s_barrier, and round 18 showed that is not
// guaranteed (intermittent post-timing divergence).
template<int EPI>
__global__ __launch_bounds__(256) void hgemm_kernel(
    const f16* __restrict__ A16, const f16* __restrict__ B, int K,
    const float* __restrict__ cosT, const float* __restrict__ sinT,
    f16* __restrict__ Qout, f16* __restrict__ Kout, f16* __restrict__ Vtout,
    const float* __restrict__ bias, float* __restrict__ Cout) {
  constexpr int BN = (EPI == 0) ? 128 : 64;
  constexpr int NJ = (EPI == 0) ? 4 : 2;
  __shared__ f16 As[2][128 * 32];
  __shared__ f16 Bs[2][BN * 32];
  const int tid = threadIdx.x;
  const int lane = tid & 63, w = tid >> 6;
  const int fr = lane & 15, fkg = lane >> 4;
  const int wm = (w >> 1) * 64;
  const int wn = (EPI == 0) ? (w & 1) * 64 : (w & 1) * 16;
  const long long rowBase = (long long)blockIdx.x * 128;
  const long long colBase = (long long)blockIdx.y * BN;

  f32x4 acc[4][NJ] = {};
  const f16* Ab = A16 + rowBase * K;
  const f16* Bb = B + colBase * K;

  const int srow = lane >> 2;
  const int kcol = ((lane & 3) ^ ((lane >> 3) & 3)) * 8;
  const int sw = (fkg ^ ((fr >> 1) & 3)) * 8;

  auto stage = [&](int buf, int k0) {
#pragma unroll
    for (int r = 0; r < 2; ++r) {
      int c = r * 4 + w;
      gload_lds16(Ab + (long long)(c * 16 + srow) * K + k0 + kcol, &As[buf][c * 512]);
    }
    if (EPI == 0) {
#pragma unroll
      for (int r = 0; r < 2; ++r) {
        int c = r * 4 + w;
        gload_lds16(Bb + (long long)(c * 16 + srow) * K + k0 + kcol, &Bs[buf][c * 512]);
      }
    } else {
      int c = w;
      gload_lds16(Bb + (long long)(c * 16 + srow) * K + k0 + kcol, &Bs[buf][c * 512]);
    }
  };

  const int NT = K >> 5;
  stage(0, 0);
  stage(1, 32);
  for (int t = 0; t < NT; ++t) {
    const int buf = t & 1;
    const int k0 = t << 5;
    if (t + 1 < NT) {
      if constexpr (EPI == 0) asm volatile("s_waitcnt vmcnt(4)" ::: "memory");
      else                    asm volatile("s_waitcnt vmcnt(3)" ::: "memory");
    } else {
      asm volatile("s_waitcnt vmcnt(0)" ::: "memory");
    }
    __builtin_amdgcn_s_barrier();            // tile t landed (all waves)
    __builtin_amdgcn_sched_barrier(0);
    half8 a[4], b[NJ];
#pragma unroll
    for (int i = 0; i < 4; ++i)
      a[i] = *(const half8*)(&As[buf][((wm >> 4) + i) * 512 + fr * 32 + sw]);
#pragma unroll
    for (int j = 0; j < NJ; ++j) {
      int chunk = (EPI == 0) ? ((wn >> 4) + j) : ((wn >> 4) + j * 2);
      b[j] = *(const half8*)(&Bs[buf][chunk * 512 + fr * 32 + sw]);
    }
    asm volatile("s_waitcnt lgkmcnt(0)" ::: "memory");  // pins reads above bar
    __builtin_amdgcn_sched_barrier(0);
    __builtin_amdgcn_s_barrier();            // all waves' reads done: WAR safe
    if (t + 2 < NT) stage(buf, k0 + 64);
#pragma unroll
    for (int i = 0; i < 4; ++i)
#pragma unroll
      for (int j = 0; j < NJ; ++j)
        acc[i][j] = __builtin_amdgcn_mfma_f32_16x16x32_f16(a[i], b[j], acc[i][j], 0, 0, 0);
  }

  if (EPI == 0) {
#pragma unroll
    for (int i = 0; i < 4; ++i) {
#pragma unroll
      for (int r = 0; r < 4; ++r) {
        int rg = (int)rowBase + wm + i * 16 + fkg * 4 + r;  // 0..4095
        int bidx = rg >> 11, nn = rg & 2047;
#pragma unroll
        for (int j = 0; j < 4; ++j) {
          int cg = (int)colBase + wn + j * 16 + fr;          // 0..3071
          int t = cg >> 10, cc = cg & 1023;
          int head = cc >> 6, d = cc & 63;
          int bh = bidx * 16 + head;
          float v = acc[i][j][r];
          if (t == 2) {
            Vtout[((long long)bh * 64 + d) * 2048 + nn] = (f16)v;
          } else {
            float pal = acc[i][j ^ 2][r];                    // partner col d^32
            float cs = cosT[nn * 64 + d];
            float sn = sinT[nn * 64 + d];
            v = v * cs + (d < 32 ? -pal : pal) * sn;         // rotate_half
            if (t == 0) v *= QSCALE;                         // d^-0.5 * log2e
            f16 hv = (f16)v;
            if (t == 0) Qout[((long long)bh * 2048 + nn) * 64 + d] = hv;
            else        Kout[((long long)bh * 2048 + nn) * 64 + d] = hv;
          }
        }
      }
    }
  } else {
#pragma unroll
    for (int i = 0; i < 4; ++i)
#pragma unroll
      for (int r = 0; r < 4; ++r) {
        long long rg = rowBase + wm + i * 16 + fkg * 4 + r;
#pragma unroll
        for (int j = 0; j < NJ; ++j) {
          int cg = (int)colBase + wn + j * 32 + fr;
          Cout[rg * 1024 + cg] = acc[i][j][r] + bias[cg];
        }
      }
  }
}

// ---------------- flash attention ------------------------------------------
// Round-16 structure (m=2, 512 blocks, in-reg P via K-row permutation,
// counted vmcnt, pkrtz softmax) + negsh4 C-in (round 18; not implicated in
// the race — attn's fence chain lgkm(0)+sched_barrier+s_barrier pins all
// LDS reads above the barrier before the same-buffer restage).
__global__ __launch_bounds__(256) void attn_kernel(
    const f16* __restrict__ Q, const f16* __restrict__ Kb,
    const f16* __restrict__ Vt, f16* __restrict__ Om) {
  __shared__ f16 Ks[2][64 * 64];
  __shared__ f16 Vs[2][64 * 64];
  const int tid = threadIdx.x;
  const int lane = tid & 63, w = tid >> 6;
  const int fr = lane & 15, fkg = lane >> 4, fk = fkg * 8;

  // XCD-aware decode: 512 blocks; xcd = lin&7 owns bh in [xcd*4, xcd*4+4)
  const int lin = blockIdx.x;
  const int slot = lin >> 3;
  const int bh = (lin & 7) * 4 + (slot >> 4);
  const int q0 = (slot & 15) * 128 + w * 32;

  const f16* Kbh = Kb + (long long)bh * 2048 * 64;
  const f16* Vbh = Vt + (long long)bh * 64 * 2048;

  // Q fragments: aq[m][ks] for q = q0 + m*16 + fr, d = ks*32 + fk..+7
  half8 aq[2][2];
#pragma unroll
  for (int m = 0; m < 2; ++m)
#pragma unroll
    for (int ks = 0; ks < 2; ++ks)
      aq[m][ks] = *(const half8*)(Q + ((long long)bh * 2048 + q0 + m * 16 + fr) * 64 +
                                  ks * 32 + fk);

  // ones A-fragment: row 0 all-ones -> l[q] = sum_kv P[q][kv] in C row 0
  half8 ones_frag;
#pragma unroll
  for (int j = 0; j < 8; ++j) ones_frag[j] = (fr == 0) ? (f16)1.0f : (f16)0.0f;

  f32x4 acc[2][4] = {};   // O^T fragments: [m][dd], col=q(fr), row=d-part
  f32x4 accL[2] = {};     // l in C row 0 (lanes fkg==0, reg 0)
  const f32x4 negsh4 = {-SHIFT2, -SHIFT2, -SHIFT2, -SHIFT2};

  // staging lane map: row (l>>3) within 8-row chunk, subchunk (l&7)^(l>>3)
  const int srow = lane >> 3;
  const int ssub = ((lane & 7) ^ srow) * 8;
  // K row permutation f(R): row bits (ks,h,fkg,r) -> source kv (ks,fkg,h,r)
  long long koff[2], voff[2];
  int ldst[2];
#pragma unroll
  for (int c = 0; c < 2; ++c) {
    int R = w * 16 + c * 8 + srow;
    int pr = (R & 0x23) | ((R & 0x0C) << 1) | ((R & 0x10) >> 2);
    koff[c] = (long long)pr * 64 + ssub;
    voff[c] = (long long)R * 2048 + ssub;
    ldst[c] = (w * 16 + c * 8) * 64;
  }
  const f16* kpt = Kbh;   // next K tile to stage (+4096 halfs per tile)
  const f16* vpt = Vbh;   // next V tile to stage (+64 halfs per tile)

  auto stage = [&](int buf) {
#pragma unroll
    for (int c = 0; c < 2; ++c) {
      gload_lds16(kpt + koff[c], &Ks[buf][ldst[c]]);
      gload_lds16(vpt + voff[c], &Vs[buf][ldst[c]]);
    }
    kpt += 4096;
    vpt += 64;
  };

  stage(0);
  stage(1);

  auto body = [&](int t, int buf) {
    if (t < 31) asm volatile("s_waitcnt vmcnt(4)" ::: "memory");
    else        asm volatile("s_waitcnt vmcnt(0)" ::: "memory");
    __builtin_amdgcn_s_barrier();          // tile t landed (all waves)
    __builtin_amdgcn_sched_barrier(0);

    // S^T = K Q^T on permuted K rows; C-in of first MFMA = negsh4 (no movs)
    f32x4 z[2][4];
#pragma unroll
    for (int n = 0; n < 4; ++n) {
      half8 bk0 = *(const half8*)(&Ks[buf][(n * 16 + fr) * 64 + ((fkg ^ (fr & 7)) * 8)]);
      half8 bk1 = *(const half8*)(&Ks[buf][(n * 16 + fr) * 64 + (((4 | fkg) ^ (fr & 7)) * 8)]);
#pragma unroll
      for (int m = 0; m < 2; ++m) {
        f32x4 tz = __builtin_amdgcn_mfma_f32_16x16x32_f16(bk0, aq[m][0], negsh4, 0, 0, 0);
        tz = __builtin_amdgcn_mfma_f32_16x16x32_f16(bk1, aq[m][1], tz, 0, 0, 0);
        z[m][n] = tz;
      }
    }

    // V fragments issued before softmax (latency hides under exp2)
    half8 av[2][4];
#pragma unroll
    for (int ks = 0; ks < 2; ++ks)
#pragma unroll
      for (int dd = 0; dd < 4; ++dd)
        av[ks][dd] = *(const half8*)(&Vs[buf][(dd * 16 + fr) * 64 +
                                              ((((ks << 2) | fkg) ^ (fr & 7)) * 8)]);

    // softmax: P = 2^z, packed straight into PV B-fragments (no LDS)
    half8 ap[2][2];
#pragma unroll
    for (int m = 0; m < 2; ++m)
#pragma unroll
      for (int ks = 0; ks < 2; ++ks) {
        union { half8 v; fp16x2 p[4]; } u;
        u.p[0] = __builtin_amdgcn_cvt_pkrtz(
            __builtin_amdgcn_exp2f(z[m][2 * ks][0]),
            __builtin_amdgcn_exp2f(z[m][2 * ks][1]));
        u.p[1] = __builtin_amdgcn_cvt_pkrtz(
            __builtin_amdgcn_exp2f(z[m][2 * ks][2]),
            __builtin_amdgcn_exp2f(z[m][2 * ks][3]));
        u.p[2] = __builtin_amdgcn_cvt_pkrtz(
            __builtin_amdgcn_exp2f(z[m][2 * ks + 1][0]),
            __builtin_amdgcn_exp2f(z[m][2 * ks + 1][1]));
        u.p[3] = __builtin_amdgcn_cvt_pkrtz(
            __builtin_amdgcn_exp2f(z[m][2 * ks + 1][2]),
            __builtin_amdgcn_exp2f(z[m][2 * ks + 1][3]));
        ap[m][ks] = u.v;
      }

    // O^T += V^T P^T  (A = V^T rows d, B = in-reg P; ones row -> l)
#pragma unroll
    for (int ks = 0; ks < 2; ++ks) {
#pragma unroll
      for (int m = 0; m < 2; ++m)
        accL[m] = __builtin_amdgcn_mfma_f32_16x16x32_f16(ones_frag, ap[m][ks], accL[m], 0, 0, 0);
#pragma unroll
      for (int dd = 0; dd < 4; ++dd)
#pragma unroll
        for (int m = 0; m < 2; ++m)
          acc[m][dd] = __builtin_amdgcn_mfma_f32_16x16x32_f16(av[ks][dd], ap[m][ks], acc[m][dd], 0, 0, 0);
    }

    asm volatile("s_waitcnt lgkmcnt(0)" ::: "memory");  // pins reads above bar
    __builtin_amdgcn_sched_barrier(0);
    __builtin_amdgcn_s_barrier();          // all waves' reads done: WAR safe
    if (t < 30) stage(buf);                // refill buf for tile t+2
  };

  for (int t = 0; t < 32; t += 2) {        // manual 2x unroll: buf literal
    body(t, 0);
    body(t + 1, 1);
  }

  // epilogue: lane holds q = q0+m*16+fr, d = dd*16 + fkg*4 + r
  const int b = bh >> 4, h = bh & 15;
#pragma unroll
  for (int m = 0; m < 2; ++m) {
    float l = __shfl(accL[m][0], fr);      // l[q] lives in lane fr (fkg=0), reg 0
    float inv = 1.f / l;
#pragma unroll
    for (int dd = 0; dd < 4; ++dd) {
      half4v o;
#pragma unroll
      for (int r = 0; r < 4; ++r) o[r] = (f16)(acc[m][dd][r] * inv);
      *(half4v*)(&Om[((long long)b * 2048 + q0 + m * 16 + fr) * 1024 +
                     h * 64 + dd * 16 + fkg * 4]) = o;
    }
  }
}

extern "C" void kernel_launch(void* const* d_in, const int* in_sizes, int n_in,
                              void* d_out, int out_size, void* d_ws, size_t ws_size,
                              hipStream_t stream) {
  (void)in_sizes; (void)n_in; (void)out_size; (void)ws_size;
  const float* x     = (const float*)d_in[0];   // [2,2048,1024]
  const float* Wqkv  = (const float*)d_in[1];   // [3072,1024]
  const float* Wproj = (const float*)d_in[2];   // [1024,1024]
  const float* bproj = (const float*)d_in[3];   // [1024]
  const float* sinT  = (const float*)d_in[4];   // [2048,64]
  const float* cosT  = (const float*)d_in[5];   // [2048,64]
  float* out = (float*)d_out;                   // [2,2048,1024] fp32

  // 40 MB layout (evidenced since round 4). Om aliases xh (dead after
  // hgemm<0>; same-stream ordering; cvt rewrites xh every call).
  f16* ws     = (f16*)d_ws;
  f16* xh     = ws;                    // [0, 4194304)
  f16* Om     = ws;                    // [0, 4194304)  (after hgemm<0>)
  f16* Wqkvh  = ws + 4194304;          // [4194304, 7340032)
  f16* Wprojh = ws + 7340032;          // [7340032, 8388608)
  f16* Qb     = ws + 8388608;          // [8388608, 12582912)   [32][2048][64]
  f16* Kb     = ws + 12582912;         // [12582912, 16777216)  [32][2048][64]
  f16* Vtb    = ws + 16777216;         // [16777216, 20971520)  [32][64][2048]

  cvt_all_kernel<<<8192, 256, 0, stream>>>(x, Wqkv, Wproj, xh, Wqkvh, Wprojh);

  hgemm_kernel<0><<<dim3(32, 24), 256, 0, stream>>>(
      xh, Wqkvh, 1024, cosT, sinT, Qb, Kb, Vtb, nullptr, nullptr);

  attn_kernel<<<512, 256, 0, stream>>>(Qb, Kb, Vtb, Om);

  hgemm_kernel<1><<<dim3(32, 16), 256, 0, stream>>>(
      Om, Wprojh, 1024, nullptr, nullptr, nullptr, nullptr, nullptr, bproj, out);
}

// Round 20
// 119.032 us; speedup vs baseline: 1.1250x; 1.0119x over previous
//
#include <hip/hip_runtime.h>
#include <hip/hip_fp16.h>

typedef _Float16 f16;
typedef _Float16 half8 __attribute__((ext_vector_type(8)));
typedef _Float16 half4v __attribute__((ext_vector_type(4)));
typedef __fp16 fp16x2 __attribute__((ext_vector_type(2)));   // cvt_pkrtz result type
typedef float f32x4 __attribute__((ext_vector_type(4)));

// Q pre-scale: d^-0.5 (=0.125) * log2(e), so attn computes P=2^(s'-12*log2e)
#define QSCALE 0.18033688011112042f
#define SHIFT2 17.312340490667560f   // 12 * log2(e)

__device__ __forceinline__ void gload_lds16(const void* g, void* lds) {
  __builtin_amdgcn_global_load_lds(
      (__attribute__((address_space(1))) void*)g,
      (__attribute__((address_space(3))) void*)lds, 16, 0, 0);
}

// ---------------- fp32 -> fp16 convert (all three inputs, one launch) ------
__global__ __launch_bounds__(256) void cvt_all_kernel(
    const float* __restrict__ x, const float* __restrict__ wqkv,
    const float* __restrict__ wproj, f16* __restrict__ xh,
    f16* __restrict__ wqkvh, f16* __restrict__ wprojh) {
  int i = blockIdx.x * 256 + threadIdx.x;      // 0 .. 2097151 (exact grid)
  const float* src; f16* dst; int off;
  if (i < 1048576)      { src = x;     dst = xh;     off = i; }
  else if (i < 1835008) { src = wqkv;  dst = wqkvh;  off = i - 1048576; }
  else                  { src = wproj; dst = wprojh; off = i - 1835008; }
  float4 v = ((const float4*)src)[off];
  half4v o;
  o.x = (f16)v.x; o.y = (f16)v.y; o.z = (f16)v.z; o.w = (f16)v.w;
  ((half4v*)dst)[off] = o;
}

// ---------------- HGEMM: C = A * B^T  (FROZEN, race-safe VAR0 ledger) ------
// BM=128, BK=32; EPI0: BN=128 (RoPE partner j^2); EPI1: BN=64.
// 2-buffer, 2-barrier loop: ds_reads -> lgkmcnt(0) asm (memory clobber, pins
// reads ABOVE the barrier) -> sched_barrier -> s_barrier -> stage.
template<int EPI>
__global__ __launch_bounds__(256) void hgemm_kernel(
    const f16* __restrict__ A16, const f16* __restrict__ B, int K,
    const float* __restrict__ cosT, const float* __restrict__ sinT,
    f16* __restrict__ Qout, f16* __restrict__ Kout, f16* __restrict__ Vtout,
    const float* __restrict__ bias, float* __restrict__ Cout) {
  constexpr int BN = (EPI == 0) ? 128 : 64;
  constexpr int NJ = (EPI == 0) ? 4 : 2;
  __shared__ f16 As[2][128 * 32];
  __shared__ f16 Bs[2][BN * 32];
  const int tid = threadIdx.x;
  const int lane = tid & 63, w = tid >> 6;
  const int fr = lane & 15, fkg = lane >> 4;
  const int wm = (w >> 1) * 64;
  const int wn = (EPI == 0) ? (w & 1) * 64 : (w & 1) * 16;
  const long long rowBase = (long long)blockIdx.x * 128;
  const long long colBase = (long long)blockIdx.y * BN;

  f32x4 acc[4][NJ] = {};
  const f16* Ab = A16 + rowBase * K;
  const f16* Bb = B + colBase * K;

  const int srow = lane >> 2;
  const int kcol = ((lane & 3) ^ ((lane >> 3) & 3)) * 8;
  const int sw = (fkg ^ ((fr >> 1) & 3)) * 8;

  auto stage = [&](int buf, int k0) {
#pragma unroll
    for (int r = 0; r < 2; ++r) {
      int c = r * 4 + w;
      gload_lds16(Ab + (long long)(c * 16 + srow) * K + k0 + kcol, &As[buf][c * 512]);
    }
    if (EPI == 0) {
#pragma unroll
      for (int r = 0; r < 2; ++r) {
        int c = r * 4 + w;
        gload_lds16(Bb + (long long)(c * 16 + srow) * K + k0 + kcol, &Bs[buf][c * 512]);
      }
    } else {
      int c = w;
      gload_lds16(Bb + (long long)(c * 16 + srow) * K + k0 + kcol, &Bs[buf][c * 512]);
    }
  };

  const int NT = K >> 5;
  stage(0, 0);
  stage(1, 32);
  for (int t = 0; t < NT; ++t) {
    const int buf = t & 1;
    const int k0 = t << 5;
    if (t + 1 < NT) {
      if constexpr (EPI == 0) asm volatile("s_waitcnt vmcnt(4)" ::: "memory");
      else                    asm volatile("s_waitcnt vmcnt(3)" ::: "memory");
    } else {
      asm volatile("s_waitcnt vmcnt(0)" ::: "memory");
    }
    __builtin_amdgcn_s_barrier();            // tile t landed (all waves)
    __builtin_amdgcn_sched_barrier(0);
    half8 a[4], b[NJ];
#pragma unroll
    for (int i = 0; i < 4; ++i)
      a[i] = *(const half8*)(&As[buf][((wm >> 4) + i) * 512 + fr * 32 + sw]);
#pragma unroll
    for (int j = 0; j < NJ; ++j) {
      int chunk = (EPI == 0) ? ((wn >> 4) + j) : ((wn >> 4) + j * 2);
      b[j] = *(const half8*)(&Bs[buf][chunk * 512 + fr * 32 + sw]);
    }
    asm volatile("s_waitcnt lgkmcnt(0)" ::: "memory");  // pins reads above bar
    __builtin_amdgcn_sched_barrier(0);
    __builtin_amdgcn_s_barrier();            // all waves' reads done: WAR safe
    if (t + 2 < NT) stage(buf, k0 + 64);
#pragma unroll
    for (int i = 0; i < 4; ++i)
#pragma unroll
      for (int j = 0; j < NJ; ++j)
        acc[i][j] = __builtin_amdgcn_mfma_f32_16x16x32_f16(a[i], b[j], acc[i][j], 0, 0, 0);
  }

  if (EPI == 0) {
#pragma unroll
    for (int i = 0; i < 4; ++i) {
#pragma unroll
      for (int r = 0; r < 4; ++r) {
        int rg = (int)rowBase + wm + i * 16 + fkg * 4 + r;  // 0..4095
        int bidx = rg >> 11, nn = rg & 2047;
#pragma unroll
        for (int j = 0; j < 4; ++j) {
          int cg = (int)colBase + wn + j * 16 + fr;          // 0..3071
          int t = cg >> 10, cc = cg & 1023;
          int head = cc >> 6, d = cc & 63;
          int bh = bidx * 16 + head;
          float v = acc[i][j][r];
          if (t == 2) {
            Vtout[((long long)bh * 64 + d) * 2048 + nn] = (f16)v;
          } else {
            float pal = acc[i][j ^ 2][r];                    // partner col d^32
            float cs = cosT[nn * 64 + d];
            float sn = sinT[nn * 64 + d];
            v = v * cs + (d < 32 ? -pal : pal) * sn;         // rotate_half
            if (t == 0) v *= QSCALE;                         // d^-0.5 * log2e
            f16 hv = (f16)v;
            if (t == 0) Qout[((long long)bh * 2048 + nn) * 64 + d] = hv;
            else        Kout[((long long)bh * 2048 + nn) * 64 + d] = hv;
          }
        }
      }
    }
  } else {
#pragma unroll
    for (int i = 0; i < 4; ++i)
#pragma unroll
      for (int r = 0; r < 4; ++r) {
        long long rg = rowBase + wm + i * 16 + fkg * 4 + r;
#pragma unroll
        for (int j = 0; j < NJ; ++j) {
          int cg = (int)colBase + wn + j * 32 + fr;
          Cout[rg * 1024 + cg] = acc[i][j][r] + bias[cg];
        }
      }
  }
}

// ---------------- flash attention ------------------------------------------
// Round-19 structure (m=2, 512 blocks, in-reg P via K-row permutation,
// counted vmcnt, pkrtz softmax, negsh4 C-in). This round: 2 kv-tiles per
// barrier pair (KVBLK=128 staged per buffer): barrier pairs 32->16, vmcnt
// waits halved per unit work. LDS 32->64 KB (still 2 blocks/CU; grid-capped
// at 2 anyway). Sub-tiles processed sequentially -> VGPR unchanged. Fence
// chain is the proven race-safe ledger verbatim.
__global__ __launch_bounds__(256) void attn_kernel(
    const f16* __restrict__ Q, const f16* __restrict__ Kb,
    const f16* __restrict__ Vt, f16* __restrict__ Om) {
  __shared__ f16 Ks[2][8192];        // [buf][2 tiles x 64 x 64]
  __shared__ f16 Vs[2][8192];
  const int tid = threadIdx.x;
  const int lane = tid & 63, w = tid >> 6;
  const int fr = lane & 15, fkg = lane >> 4, fk = fkg * 8;

  // XCD-aware decode: 512 blocks; xcd = lin&7 owns bh in [xcd*4, xcd*4+4)
  const int lin = blockIdx.x;
  const int slot = lin >> 3;
  const int bh = (lin & 7) * 4 + (slot >> 4);
  const int q0 = (slot & 15) * 128 + w * 32;

  const f16* Kbh = Kb + (long long)bh * 2048 * 64;
  const f16* Vbh = Vt + (long long)bh * 64 * 2048;

  // Q fragments: aq[m][ks] for q = q0 + m*16 + fr, d = ks*32 + fk..+7
  half8 aq[2][2];
#pragma unroll
  for (int m = 0; m < 2; ++m)
#pragma unroll
    for (int ks = 0; ks < 2; ++ks)
      aq[m][ks] = *(const half8*)(Q + ((long long)bh * 2048 + q0 + m * 16 + fr) * 64 +
                                  ks * 32 + fk);

  // ones A-fragment: row 0 all-ones -> l[q] = sum_kv P[q][kv] in C row 0
  half8 ones_frag;
#pragma unroll
  for (int j = 0; j < 8; ++j) ones_frag[j] = (fr == 0) ? (f16)1.0f : (f16)0.0f;

  f32x4 acc[2][4] = {};   // O^T fragments: [m][dd], col=q(fr), row=d-part
  f32x4 accL[2] = {};     // l in C row 0 (lanes fkg==0, reg 0)
  const f32x4 negsh4 = {-SHIFT2, -SHIFT2, -SHIFT2, -SHIFT2};

  // staging lane map: row (l>>3) within 8-row chunk, subchunk (l&7)^(l>>3)
  const int srow = lane >> 3;
  const int ssub = ((lane & 7) ^ srow) * 8;
  // K row permutation f(R): row bits (ks,h,fkg,r) -> source kv (ks,fkg,h,r)
  long long koff[2], voff[2];
  int ldst[2];
#pragma unroll
  for (int c = 0; c < 2; ++c) {
    int R = w * 16 + c * 8 + srow;
    int pr = (R & 0x23) | ((R & 0x0C) << 1) | ((R & 0x10) >> 2);
    koff[c] = (long long)pr * 64 + ssub;
    voff[c] = (long long)R * 2048 + ssub;
    ldst[c] = (w * 16 + c * 8) * 64;
  }
  const f16* kpt = Kbh;   // next 2-tile group to stage (+8192 halfs per iter)
  const f16* vpt = Vbh;   // (+128 halfs per iter)

  auto stage = [&](int buf) {                // 8 loads/thread: 2 tiles x K,V
#pragma unroll
    for (int s = 0; s < 2; ++s)
#pragma unroll
      for (int c = 0; c < 2; ++c) {
        gload_lds16(kpt + s * 4096 + koff[c], &Ks[buf][s * 4096 + ldst[c]]);
        gload_lds16(vpt + s * 64 + voff[c], &Vs[buf][s * 4096 + ldst[c]]);
      }
    kpt += 8192;
    vpt += 128;
  };

  stage(0);
  stage(1);

  // compute one 64-kv sub-tile from Ks/Vs[buf] at half-offset so*4096
  auto subtile = [&](int buf, int so) {
    const f16* Kt = &Ks[buf][so];
    const f16* Vtl = &Vs[buf][so];
    f32x4 z[2][4];
#pragma unroll
    for (int n = 0; n < 4; ++n) {
      half8 bk0 = *(const half8*)(&Kt[(n * 16 + fr) * 64 + ((fkg ^ (fr & 7)) * 8)]);
      half8 bk1 = *(const half8*)(&Kt[(n * 16 + fr) * 64 + (((4 | fkg) ^ (fr & 7)) * 8)]);
#pragma unroll
      for (int m = 0; m < 2; ++m) {
        f32x4 tz = __builtin_amdgcn_mfma_f32_16x16x32_f16(bk0, aq[m][0], negsh4, 0, 0, 0);
        tz = __builtin_amdgcn_mfma_f32_16x16x32_f16(bk1, aq[m][1], tz, 0, 0, 0);
        z[m][n] = tz;
      }
    }

    half8 av[2][4];
#pragma unroll
    for (int ks = 0; ks < 2; ++ks)
#pragma unroll
      for (int dd = 0; dd < 4; ++dd)
        av[ks][dd] = *(const half8*)(&Vtl[(dd * 16 + fr) * 64 +
                                          ((((ks << 2) | fkg) ^ (fr & 7)) * 8)]);

    half8 ap[2][2];
#pragma unroll
    for (int m = 0; m < 2; ++m)
#pragma unroll
      for (int ks = 0; ks < 2; ++ks) {
        union { half8 v; fp16x2 p[4]; } u;
        u.p[0] = __builtin_amdgcn_cvt_pkrtz(
            __builtin_amdgcn_exp2f(z[m][2 * ks][0]),
            __builtin_amdgcn_exp2f(z[m][2 * ks][1]));
        u.p[1] = __builtin_amdgcn_cvt_pkrtz(
            __builtin_amdgcn_exp2f(z[m][2 * ks][2]),
            __builtin_amdgcn_exp2f(z[m][2 * ks][3]));
        u.p[2] = __builtin_amdgcn_cvt_pkrtz(
            __builtin_amdgcn_exp2f(z[m][2 * ks + 1][0]),
            __builtin_amdgcn_exp2f(z[m][2 * ks + 1][1]));
        u.p[3] = __builtin_amdgcn_cvt_pkrtz(
            __builtin_amdgcn_exp2f(z[m][2 * ks + 1][2]),
            __builtin_amdgcn_exp2f(z[m][2 * ks + 1][3]));
        ap[m][ks] = u.v;
      }

#pragma unroll
    for (int ks = 0; ks < 2; ++ks) {
#pragma unroll
      for (int m = 0; m < 2; ++m)
        accL[m] = __builtin_amdgcn_mfma_f32_16x16x32_f16(ones_frag, ap[m][ks], accL[m], 0, 0, 0);
#pragma unroll
      for (int dd = 0; dd < 4; ++dd)
#pragma unroll
        for (int m = 0; m < 2; ++m)
          acc[m][dd] = __builtin_amdgcn_mfma_f32_16x16x32_f16(av[ks][dd], ap[m][ks], acc[m][dd], 0, 0, 0);
    }
  };

  for (int it = 0; it < 16; ++it) {
    const int buf = it & 1;
    if (it < 15) asm volatile("s_waitcnt vmcnt(8)" ::: "memory");
    else         asm volatile("s_waitcnt vmcnt(0)" ::: "memory");
    __builtin_amdgcn_s_barrier();          // this buffer's 2 tiles landed
    __builtin_amdgcn_sched_barrier(0);

    subtile(buf, 0);
    subtile(buf, 4096);

    asm volatile("s_waitcnt lgkmcnt(0)" ::: "memory");  // pins reads above bar
    __builtin_amdgcn_sched_barrier(0);
    __builtin_amdgcn_s_barrier();          // all waves' reads done: WAR safe
    if (it < 14) stage(buf);               // refill buf for iter it+2
  }

  // epilogue: lane holds q = q0+m*16+fr, d = dd*16 + fkg*4 + r
  const int b = bh >> 4, h = bh & 15;
#pragma unroll
  for (int m = 0; m < 2; ++m) {
    float l = __shfl(accL[m][0], fr);      // l[q] lives in lane fr (fkg=0), reg 0
    float inv = 1.f / l;
#pragma unroll
    for (int dd = 0; dd < 4; ++dd) {
      half4v o;
#pragma unroll
      for (int r = 0; r < 4; ++r) o[r] = (f16)(acc[m][dd][r] * inv);
      *(half4v*)(&Om[((long long)b * 2048 + q0 + m * 16 + fr) * 1024 +
                     h * 64 + dd * 16 + fkg * 4]) = o;
    }
  }
}

extern "C" void kernel_launch(void* const* d_in, const int* in_sizes, int n_in,
                              void* d_out, int out_size, void* d_ws, size_t ws_size,
                              hipStream_t stream) {
  (void)in_sizes; (void)n_in; (void)out_size; (void)ws_size;
  const float* x     = (const float*)d_in[0];   // [2,2048,1024]
  const float* Wqkv  = (const float*)d_in[1];   // [3072,1024]
  const float* Wproj = (const float*)d_in[2];   // [1024,1024]
  const float* bproj = (const float*)d_in[3];   // [1024]
  const float* sinT  = (const float*)d_in[4];   // [2048,64]
  const float* cosT  = (const float*)d_in[5];   // [2048,64]
  float* out = (float*)d_out;                   // [2,2048,1024] fp32

  // 40 MB layout (evidenced since round 4). Om aliases xh (dead after
  // hgemm<0>; same-stream ordering; cvt rewrites xh every call).
  f16* ws     = (f16*)d_ws;
  f16* xh     = ws;                    // [0, 4194304)
  f16* Om     = ws;                    // [0, 4194304)  (after hgemm<0>)
  f16* Wqkvh  = ws + 4194304;          // [4194304, 7340032)
  f16* Wprojh = ws + 7340032;          // [7340032, 8388608)
  f16* Qb     = ws + 8388608;          // [8388608, 12582912)   [32][2048][64]
  f16* Kb     = ws + 12582912;         // [12582912, 16777216)  [32][2048][64]
  f16* Vtb    = ws + 16777216;         // [16777216, 20971520)  [32][64][2048]

  cvt_all_kernel<<<8192, 256, 0, stream>>>(x, Wqkv, Wproj, xh, Wqkvh, Wprojh);

  hgemm_kernel<0><<<dim3(32, 24), 256, 0, stream>>>(
      xh, Wqkvh, 1024, cosT, sinT, Qb, Kb, Vtb, nullptr, nullptr);

  attn_kernel<<<512, 256, 0, stream>>>(Qb, Kb, Vtb, Om);

  hgemm_kernel<1><<<dim3(32, 16), 256, 0, stream>>>(
      Om, Wprojh, 1024, nullptr, nullptr, nullptr, nullptr, nullptr, bproj, out);
}